// Round 1
// baseline (71.752 us; speedup 1.0000x reference)
//
#include <hip/hip_runtime.h>
#include <math.h>

// Inter-prediction: 21x21 search, 4x4 blocks, softmax(-100*meanAbsDiff) weights.
// One wave per 4x4 output block; one 256-thread WG = 4 waves = 2x2 block tile
// sharing a 28x28 im2_pad window in LDS. Online softmax so each shift's 4x4
// window values are read from LDS exactly once (SAD + weighted acc fused).

#define HH 256
#define WW 256
#define SSZ 21
#define PAD 10
#define NSH 441   // 21*21
#define WIN 28    // 2*4 + 21 - 1

__global__ __launch_bounds__(256) void pred_kernel(
    const float* __restrict__ im1, const float* __restrict__ im2,
    float* __restrict__ out) {
  __shared__ float win[WIN * WIN];

  const int tid = threadIdx.x;
  const int T = blockIdx.x;
  const int b = T >> 10;           // 1024 tiles (32x32) per batch image
  const int rem = T & 1023;
  const int tr = rem >> 5;
  const int tc = rem & 31;
  const float* im2b = im2 + b * (HH * WW);

  // Stage 28x28 zero-padded im2 window for this 2x2 block tile.
  for (int e = tid; e < WIN * WIN; e += 256) {
    int wr = e / WIN;
    int wc = e - wr * WIN;
    int gr = tr * 8 + wr - PAD;
    int gc = tc * 8 + wc - PAD;
    float v = 0.f;
    if ((unsigned)gr < HH && (unsigned)gc < WW) v = im2b[gr * WW + gc];
    win[e] = v;
  }
  __syncthreads();

  const int wave = tid >> 6;
  const int lane = tid & 63;
  const int by = tr * 2 + (wave >> 1);
  const int bx = tc * 2 + (wave & 1);
  const int wbase = ((wave >> 1) * 4) * WIN + (wave & 1) * 4;

  // im1 4x4 block, broadcast into every lane's registers (aligned float4 rows).
  float a[16];
  const float* im1b = im1 + b * (HH * WW) + (by * 4) * WW + bx * 4;
#pragma unroll
  for (int dy = 0; dy < 4; ++dy) {
    const float4 r = *reinterpret_cast<const float4*>(im1b + dy * WW);
    a[dy * 4 + 0] = r.x; a[dy * 4 + 1] = r.y;
    a[dy * 4 + 2] = r.z; a[dy * 4 + 3] = r.w;
  }

  // logits = -100 * (sad/16) = -6.25*sad; use exp2: c = 6.25*log2(e)
  const float cc = 9.016844005556021f;
  float m = 1e30f, l = 0.f;
  float o[16];
#pragma unroll
  for (int t = 0; t < 16; ++t) o[t] = 0.f;

  int i = lane / 21;
  int j = lane - i * 21;
  for (int k = lane; k < NSH; k += 64) {
    const float* wp = &win[wbase + i * WIN + j];
    float wv[16];
#pragma unroll
    for (int dy = 0; dy < 4; ++dy)
#pragma unroll
      for (int dx = 0; dx < 4; ++dx) wv[dy * 4 + dx] = wp[dy * WIN + dx];

    float s0 = 0.f, s1 = 0.f, s2 = 0.f, s3 = 0.f;
#pragma unroll
    for (int dy = 0; dy < 4; ++dy) {
      s0 += fabsf(a[dy * 4 + 0] - wv[dy * 4 + 0]);
      s1 += fabsf(a[dy * 4 + 1] - wv[dy * 4 + 1]);
      s2 += fabsf(a[dy * 4 + 2] - wv[dy * 4 + 2]);
      s3 += fabsf(a[dy * 4 + 3] - wv[dy * 4 + 3]);
    }
    const float v = (s0 + s1) + (s2 + s3);

    // online softmax update (m = running min SAD)
    const float mn = fminf(m, v);
    const float beta = __builtin_amdgcn_exp2f(cc * (mn - m));  // arg <= 0
    const float p = __builtin_amdgcn_exp2f(cc * (mn - v));     // arg <= 0
    m = mn;
    l = l * beta + p;
#pragma unroll
    for (int t = 0; t < 16; ++t) o[t] = __builtin_fmaf(o[t], beta, p * wv[t]);

    // advance shift index by 64: (i,j) += (3,1) with base-21 carry
    j += 1; i += 3;
    if (j >= 21) { j -= 21; i += 1; }
  }

  // Cross-lane merge: global min, one rescale, butterfly sums.
  const float lm = m;
#pragma unroll
  for (int off = 32; off; off >>= 1) m = fminf(m, __shfl_xor(m, off, 64));
  const float beta = __builtin_amdgcn_exp2f(cc * (m - lm));  // arg <= 0
  l *= beta;
#pragma unroll
  for (int t = 0; t < 16; ++t) o[t] *= beta;
#pragma unroll
  for (int off = 32; off; off >>= 1) {
    l += __shfl_xor(l, off, 64);
#pragma unroll
    for (int t = 0; t < 16; ++t) o[t] += __shfl_xor(o[t], off, 64);
  }

  const float rinv = __builtin_amdgcn_rcpf(l);  // l >= 1 always
  if (lane == 0) {
    float* op = out + b * (HH * WW) + (by * 4) * WW + bx * 4;
#pragma unroll
    for (int dy = 0; dy < 4; ++dy) {
      float4 v4 = make_float4(o[dy * 4 + 0] * rinv, o[dy * 4 + 1] * rinv,
                              o[dy * 4 + 2] * rinv, o[dy * 4 + 3] * rinv);
      *reinterpret_cast<float4*>(op + dy * WW) = v4;
    }
  }
}

extern "C" void kernel_launch(void* const* d_in, const int* in_sizes, int n_in,
                              void* d_out, int out_size, void* d_ws, size_t ws_size,
                              hipStream_t stream) {
  const float* im1 = (const float*)d_in[0];
  const float* im2 = (const float*)d_in[1];
  float* out = (float*)d_out;
  const int B = in_sizes[0] / (HH * WW);  // 2
  pred_kernel<<<B * 1024, 256, 0, stream>>>(im1, im2, out);
}

// Round 2
// 65.334 us; speedup vs baseline: 1.0982x; 1.0982x over previous
//
#include <hip/hip_runtime.h>
#include <math.h>

// Inter-prediction: 21x21 search, 4x4 blocks, softmax(-100*meanAbsDiff).
// One wave per 4x4 block; WG=256 (4 waves) = 2x2 block tile sharing a 28x28
// im2_pad window in LDS (stride 29 to break bank conflicts).
//
// Lane task layout: 441 shifts = 63 lanes x 7 consecutive-j shifts.
// Lane L (<63): shift rows i=L/3, cols j0=(L%3)*7 .. j0+6. Its 7 shifts all
// read from a 4x10 register window (40 LDS reads instead of 112). Phase 1
// computes 7 SADs into registers; a wave-min gives the max logit exactly, so
// phase 2 accumulates with plain FMA — no online-softmax rescale at all.
// Final reduction: recursive-halving butterfly (15 shfl) -> lane 4t owns
// pixel t.

#define HH 256
#define WW 256
#define PAD 10
#define WINR 28
#define WSTR 29              // padded stride: worst LDS aliasing 2-way (free)
#define LDSN (WINR * WSTR)   // 812 floats = 3.2 KB

__global__ __launch_bounds__(256) void pred_kernel(
    const float* __restrict__ im1, const float* __restrict__ im2,
    float* __restrict__ out) {
  __shared__ float win[LDSN];

  const int tid = threadIdx.x;
  const int T = blockIdx.x;
  const int b = T >> 10;           // 1024 2x2-block tiles per image
  const int rem = T & 1023;
  const int tr = rem >> 5;
  const int tc = rem & 31;
  const float* im2b = im2 + b * (HH * WW);

  // Stage 28x28 zero-padded im2 window (stride 29) for this 2x2 block tile.
  for (int e = tid; e < LDSN; e += 256) {
    int wr = e / WSTR;
    int wc = e - wr * WSTR;
    int gr = tr * 8 + wr - PAD;
    int gc = tc * 8 + wc - PAD;
    float v = 0.f;
    if ((unsigned)gr < HH && (unsigned)gc < WW) v = im2b[gr * WW + gc];
    win[e] = v;
  }
  __syncthreads();

  const int wave = tid >> 6;
  const int lane = tid & 63;
  const int by = tr * 2 + (wave >> 1);
  const int bx = tc * 2 + (wave & 1);
  const int wbase = ((wave >> 1) * 4) * WSTR + (wave & 1) * 4;

  // im1 4x4 block, broadcast to all lanes (L2-resident, wave-uniform addrs).
  float a[16];
  const float* im1b = im1 + b * (HH * WW) + (by * 4) * WW + bx * 4;
#pragma unroll
  for (int dy = 0; dy < 4; ++dy) {
    const float4 r = *reinterpret_cast<const float4*>(im1b + dy * WW);
    a[dy * 4 + 0] = r.x; a[dy * 4 + 1] = r.y;
    a[dy * 4 + 2] = r.z; a[dy * 4 + 3] = r.w;
  }

  // Per-lane 4x10 register window covering its 7 shifts.
  const int i = lane / 3;          // shift row 0..20 (lane 63 -> 21, dummy)
  const int j0 = (lane - i * 3) * 7;
  const int base = wbase + i * WSTR + j0;
  float w[40];
#pragma unroll
  for (int dy = 0; dy < 4; ++dy)
#pragma unroll
    for (int c = 0; c < 10; ++c) w[dy * 10 + c] = win[base + dy * WSTR + c];

  // Phase 1: 7 SADs into registers.
  float sad[7];
#pragma unroll
  for (int t = 0; t < 7; ++t) {
    float s0 = 0.f, s1 = 0.f, s2 = 0.f, s3 = 0.f;
#pragma unroll
    for (int dy = 0; dy < 4; ++dy) {
      s0 += fabsf(a[dy * 4 + 0] - w[dy * 10 + t + 0]);
      s1 += fabsf(a[dy * 4 + 1] - w[dy * 10 + t + 1]);
      s2 += fabsf(a[dy * 4 + 2] - w[dy * 10 + t + 2]);
      s3 += fabsf(a[dy * 4 + 3] - w[dy * 10 + t + 3]);
    }
    sad[t] = (s0 + s1) + (s2 + s3);
  }
  if (lane == 63) {                // dummy lane: zero weight
#pragma unroll
    for (int t = 0; t < 7; ++t) sad[t] = 3.0e38f;
  }

  // Exact global min SAD (= max logit) before any accumulation.
  float m = sad[0];
#pragma unroll
  for (int t = 1; t < 7; ++t) m = fminf(m, sad[t]);
#pragma unroll
  for (int off = 32; off; off >>= 1) m = fminf(m, __shfl_xor(m, off, 64));

  // Phase 2: weights + plain-FMA accumulation from the same registers.
  // logit = -100*sad/16 = -6.25*sad; exp2 const = 6.25*log2(e).
  const float cc = 9.016844005556021f;
  float l = 0.f;
  float o[16];
#pragma unroll
  for (int t = 0; t < 16; ++t) o[t] = 0.f;
#pragma unroll
  for (int t = 0; t < 7; ++t) {
    const float p = __builtin_amdgcn_exp2f(cc * (m - sad[t]));  // arg <= 0
    l += p;
#pragma unroll
    for (int dy = 0; dy < 4; ++dy)
#pragma unroll
      for (int dx = 0; dx < 4; ++dx)
        o[dy * 4 + dx] = __builtin_fmaf(p, w[dy * 10 + t + dx], o[dy * 4 + dx]);
  }

  // Recursive-halving reduction: value-set halves each step.
  // After 4 steps lane holds pixel idx = b5*8+b4*4+b3*2+b2; lane 4t owns t.
  float r8[8];
  {
    const bool up = (lane & 32) != 0;
#pragma unroll
    for (int q = 0; q < 8; ++q) {
      const float send = up ? o[q] : o[q + 8];
      const float recv = __shfl_xor(send, 32, 64);
      r8[q] = (up ? o[q + 8] : o[q]) + recv;
    }
  }
  float r4[4];
  {
    const bool up = (lane & 16) != 0;
#pragma unroll
    for (int q = 0; q < 4; ++q) {
      const float send = up ? r8[q] : r8[q + 4];
      const float recv = __shfl_xor(send, 16, 64);
      r4[q] = (up ? r8[q + 4] : r8[q]) + recv;
    }
  }
  float r2[2];
  {
    const bool up = (lane & 8) != 0;
#pragma unroll
    for (int q = 0; q < 2; ++q) {
      const float send = up ? r4[q] : r4[q + 2];
      const float recv = __shfl_xor(send, 8, 64);
      r2[q] = (up ? r4[q + 2] : r4[q]) + recv;
    }
  }
  float r1;
  {
    const bool up = (lane & 4) != 0;
    const float send = up ? r2[0] : r2[1];
    const float recv = __shfl_xor(send, 4, 64);
    r1 = (up ? r2[1] : r2[0]) + recv;
  }
  r1 += __shfl_xor(r1, 2, 64);
  r1 += __shfl_xor(r1, 1, 64);

#pragma unroll
  for (int off = 32; off; off >>= 1) l += __shfl_xor(l, off, 64);
  const float rinv = __builtin_amdgcn_rcpf(l);  // l >= 1 always

  if ((lane & 3) == 0) {
    const int t = lane >> 2;       // pixel 0..15
    out[b * (HH * WW) + (by * 4 + (t >> 2)) * WW + bx * 4 + (t & 3)] =
        r1 * rinv;
  }
}

extern "C" void kernel_launch(void* const* d_in, const int* in_sizes, int n_in,
                              void* d_out, int out_size, void* d_ws, size_t ws_size,
                              hipStream_t stream) {
  const float* im1 = (const float*)d_in[0];
  const float* im2 = (const float*)d_in[1];
  float* out = (float*)d_out;
  const int B = in_sizes[0] / (HH * WW);  // 2
  pred_kernel<<<B * 1024, 256, 0, stream>>>(im1, im2, out);
}

// Round 3
// 64.340 us; speedup vs baseline: 1.1152x; 1.0155x over previous
//
#include <hip/hip_runtime.h>
#include <math.h>

// Inter-prediction: 21x21 search, 4x4 blocks, softmax(-100*meanAbsDiff).
// One wave per 4x4 block; WG=256 (4 waves) = 2x2 block tile.
//
// R3: packed-fp32 version. The 28x28 im2_pad window is staged COLUMN-MAJOR
// (stride 30) in TWO row-phase copies (copy0 rows 0..27 as-is, copy1 rows
// shifted up by 1), so any lane's 4 consecutive window rows split into two
// 8B-aligned row-pairs -> ds_read_b64 loads and v_pk_*_f32 compute:
//   SAD:    pk_sub + pk_max(d,-d) + pk_add  (24 pk-issues per 48 elem-ops)
//   accum:  v_pk_fma_f32 (8/shift instead of 16)
// 441 shifts = 63 lanes x 7 consecutive-col shifts; each lane's 7 shifts
// share a 4x10 register window (20 ds_read_b64). Exact wave-min of SAD
// before accumulation -> no online-softmax rescale. Recursive-halving
// butterfly reduction -> lane 4t owns pixel t.

typedef float v2f __attribute__((ext_vector_type(2)));

#define HH 256
#define WW 256
#define PAD 10
#define NR 28
#define NC 28
#define CSTR 30              // per-column stride (floats)
#define COPY (NC * CSTR)     // 840 floats per copy
#define LDSN (2 * COPY)      // 6720 B total

__global__ __launch_bounds__(256) void pred_kernel(
    const float* __restrict__ im1, const float* __restrict__ im2,
    float* __restrict__ out) {
  __shared__ __attribute__((aligned(16))) float win2[LDSN];

  const int tid = threadIdx.x;
  const int T = blockIdx.x;
  const int b = T >> 10;           // 1024 2x2-block tiles per image
  const int rem = T & 1023;
  const int tr = rem >> 5;
  const int tc = rem & 31;
  const float* im2b = im2 + b * (HH * WW);

  // Stage 28x28 zero-padded window, col-major stride 30, two row phases.
  for (int e = tid; e < NR * NC; e += 256) {
    const int r = e / NC;
    const int c = e - r * NC;
    const int gr = tr * 8 + r - PAD;
    const int gc = tc * 8 + c - PAD;
    float v = 0.f;
    if ((unsigned)gr < HH && (unsigned)gc < WW) v = im2b[gr * WW + gc];
    win2[c * CSTR + r] = v;                          // copy0: row r
    if (r >= 1) win2[COPY + c * CSTR + (r - 1)] = v; // copy1: row r at slot r-1
  }
  __syncthreads();

  const int wave = tid >> 6;
  const int lane = tid & 63;
  const int by = tr * 2 + (wave >> 1);
  const int bx = tc * 2 + (wave & 1);

  // im1 4x4 block as row-pair v2 per column: a2[col][rp] = {row2rp, row2rp+1}
  v2f a2[4][2];
  {
    const float* im1b = im1 + b * (HH * WW) + (by * 4) * WW + bx * 4;
    const float4 r0 = *reinterpret_cast<const float4*>(im1b + 0 * WW);
    const float4 r1 = *reinterpret_cast<const float4*>(im1b + 1 * WW);
    const float4 r2 = *reinterpret_cast<const float4*>(im1b + 2 * WW);
    const float4 r3 = *reinterpret_cast<const float4*>(im1b + 3 * WW);
    a2[0][0] = (v2f){r0.x, r1.x}; a2[1][0] = (v2f){r0.y, r1.y};
    a2[2][0] = (v2f){r0.z, r1.z}; a2[3][0] = (v2f){r0.w, r1.w};
    a2[0][1] = (v2f){r2.x, r3.x}; a2[1][1] = (v2f){r2.y, r3.y};
    a2[2][1] = (v2f){r2.z, r3.z}; a2[3][1] = (v2f){r2.w, r3.w};
  }

  // Lane's shift tile: row i, cols j0..j0+6 (lane 63: dummy).
  const int i = lane / 3;
  const int j0 = (lane - i * 3) * 7;
  const int ir = i + (wave >> 1) * 4;   // window row of shift origin
  const int jc = j0 + (wave & 1) * 4;   // window col of shift origin
  const int par = ir & 1;
  const int q0 = ir - par;              // even row slot in chosen copy
  const int baseIdx = par * COPY + jc * CSTR + q0;

  // 4x10 register window as row-pair v2s: 20 ds_read_b64.
  v2f w2[10][2];
#pragma unroll
  for (int c = 0; c < 10; ++c) {
#pragma unroll
    for (int rp = 0; rp < 2; ++rp)
      w2[c][rp] = *reinterpret_cast<const v2f*>(
          &win2[baseIdx + c * CSTR + 2 * rp]);
  }

  // Phase 1: 7 SADs (packed).
  float sad[7];
#pragma unroll
  for (int t = 0; t < 7; ++t) {
    v2f acc = (v2f){0.f, 0.f};
#pragma unroll
    for (int c = 0; c < 4; ++c) {
#pragma unroll
      for (int rp = 0; rp < 2; ++rp) {
        const v2f d = a2[c][rp] - w2[t + c][rp];
        acc += __builtin_elementwise_max(d, -d);
      }
    }
    sad[t] = acc.x + acc.y;
  }
  if (lane == 63) {
#pragma unroll
    for (int t = 0; t < 7; ++t) sad[t] = 3.0e38f;
  }

  // Exact global min SAD (= max logit).
  float m = sad[0];
#pragma unroll
  for (int t = 1; t < 7; ++t) m = fminf(m, sad[t]);
#pragma unroll
  for (int off = 32; off; off >>= 1) m = fminf(m, __shfl_xor(m, off, 64));

  // Phase 2: weights + packed FMA accumulation.
  // logit = -6.25*sad; exp2 const cc = 6.25*log2(e).
  const float cc = 9.016844005556021f;
  const float cm = cc * m;
  float l = 0.f;
  v2f o2[4][2];
#pragma unroll
  for (int c = 0; c < 4; ++c)
#pragma unroll
    for (int rp = 0; rp < 2; ++rp) o2[c][rp] = (v2f){0.f, 0.f};
#pragma unroll
  for (int t = 0; t < 7; ++t) {
    const float p = __builtin_amdgcn_exp2f(__builtin_fmaf(-cc, sad[t], cm));
    l += p;
    const v2f pv = (v2f){p, p};
#pragma unroll
    for (int c = 0; c < 4; ++c)
#pragma unroll
      for (int rp = 0; rp < 2; ++rp)
        o2[c][rp] += pv * w2[t + c][rp];   // contracts to v_pk_fma_f32
  }

  // Unpack to o[dy*4+dx] and recursive-halving reduce; lane 4t owns pixel t.
  float o[16];
#pragma unroll
  for (int c = 0; c < 4; ++c)
#pragma unroll
    for (int rp = 0; rp < 2; ++rp) {
      o[(2 * rp + 0) * 4 + c] = o2[c][rp].x;
      o[(2 * rp + 1) * 4 + c] = o2[c][rp].y;
    }

  float r8[8];
  {
    const bool up = (lane & 32) != 0;
#pragma unroll
    for (int q = 0; q < 8; ++q) {
      const float send = up ? o[q] : o[q + 8];
      const float recv = __shfl_xor(send, 32, 64);
      r8[q] = (up ? o[q + 8] : o[q]) + recv;
    }
  }
  float r4[4];
  {
    const bool up = (lane & 16) != 0;
#pragma unroll
    for (int q = 0; q < 4; ++q) {
      const float send = up ? r8[q] : r8[q + 4];
      const float recv = __shfl_xor(send, 16, 64);
      r4[q] = (up ? r8[q + 4] : r8[q]) + recv;
    }
  }
  float r2[2];
  {
    const bool up = (lane & 8) != 0;
#pragma unroll
    for (int q = 0; q < 2; ++q) {
      const float send = up ? r4[q] : r4[q + 2];
      const float recv = __shfl_xor(send, 8, 64);
      r2[q] = (up ? r4[q + 2] : r4[q]) + recv;
    }
  }
  float r1;
  {
    const bool up = (lane & 4) != 0;
    const float send = up ? r2[0] : r2[1];
    const float recv = __shfl_xor(send, 4, 64);
    r1 = (up ? r2[1] : r2[0]) + recv;
  }
  r1 += __shfl_xor(r1, 2, 64);
  r1 += __shfl_xor(r1, 1, 64);

#pragma unroll
  for (int off = 32; off; off >>= 1) l += __shfl_xor(l, off, 64);
  const float rinv = __builtin_amdgcn_rcpf(l);  // l >= 1 always

  if ((lane & 3) == 0) {
    const int t = lane >> 2;       // pixel 0..15
    out[b * (HH * WW) + (by * 4 + (t >> 2)) * WW + bx * 4 + (t & 3)] =
        r1 * rinv;
  }
}

extern "C" void kernel_launch(void* const* d_in, const int* in_sizes, int n_in,
                              void* d_out, int out_size, void* d_ws, size_t ws_size,
                              hipStream_t stream) {
  const float* im1 = (const float*)d_in[0];
  const float* im2 = (const float*)d_in[1];
  float* out = (float*)d_out;
  const int B = in_sizes[0] / (HH * WW);  // 2
  pred_kernel<<<B * 1024, 256, 0, stream>>>(im1, im2, out);
}